// Round 5
// baseline (165.385 us; speedup 1.0000x reference)
//
#include <hip/hip_runtime.h>
#include <math.h>

#define SEQ    4096
#define DH     64
#define DMODEL 1024
#define NBH    32
#define NT64   64               // 64-key tiles per bh
#define LOG2E  1.44269504088896340736f

typedef __attribute__((ext_vector_type(8)))  short short8;
typedef __attribute__((ext_vector_type(4)))  float f32x4;
typedef __attribute__((ext_vector_type(16))) float f32x16;
typedef __attribute__((ext_vector_type(2)))  unsigned uint2v;

// ws layout (bytes):
//   [0, 33554432)            KV fragments: 32 bh x 64 tiles x 16384 B
//   [33554432, 67108864)     bf16 partials: 1024 pid x 32768 B   (split mode)
//   [67108864, 68157440)     f32 lsums: 1024 pid x 1024 B        (split mode)
#define WS_KV_BYTES   33554432ull
#define WS_NEED_SPLIT 68157440ull

__device__ __forceinline__ unsigned short f2bf(float f) {
  union { float f; unsigned u; } x; x.f = f;
  unsigned r = x.u + 0x7FFFu + ((x.u >> 16) & 1u);   // RNE
  return (unsigned short)(r >> 16);
}
__device__ __forceinline__ float bf2f(unsigned short u) {
  union { unsigned u; float f; } x; x.u = ((unsigned)u) << 16;
  return x.f;
}
__device__ __forceinline__ unsigned cvtpk_bf16(float lo, float hi) {
  unsigned r;
  asm("v_cvt_pk_bf16_f32 %0, %1, %2" : "=v"(r) : "v"(lo), "v"(hi));
  return r;
}

// ---------------------------------------------------------------------------
// Prepass: bf16 K/V in MFMA-fragment order, per 64-key tile (16 KB each):
//   tile t: [K 8192 B][V 8192 B]
//   K chunk ((kb2*4 + d4)*2 + hi)*32 + l31  -> K[kb2*32+l31][d4*16+hi*8 ..+7]
//   V chunk ((k162*2 + hi)*64 + dt*32 + l31) -> V[k162*16+hi*8+j][dt*32+l31]
// ---------------------------------------------------------------------------
__global__ __launch_bounds__(256)
void prep(const float* __restrict__ Kp, const float* __restrict__ Vp,
          unsigned short* __restrict__ ws) {
  __shared__ unsigned short Kt[128 * DH];
  __shared__ unsigned short Vt[128 * DH];
  const int blk = blockIdx.x;              // bh*32 + t128
  const int bh = blk >> 5, t128 = blk & 31;
  const int b = bh >> 4, h = bh & 15;
  const size_t gbase = (size_t)b * SEQ * DMODEL + (size_t)h * DH +
                       (size_t)t128 * 128 * DMODEL;
  const float* Kb = Kp + gbase;
  const float* Vb = Vp + gbase;
  unsigned short* wt = ws + (size_t)bh * NT64 * 8192 + (size_t)(2 * t128) * 8192;
  const int tid = threadIdx.x;

#pragma unroll
  for (int c = 0; c < 8; ++c) {
    const int idx = c * 256 + tid;
    const int row = idx >> 4, dc = idx & 15;
    f32x4 kf = *(const f32x4*)(Kb + (size_t)row * DMODEL + dc * 4);
    f32x4 vf = *(const f32x4*)(Vb + (size_t)row * DMODEL + dc * 4);
    uint2v ku, vu;
    ku[0] = (unsigned)f2bf(kf[0]) | ((unsigned)f2bf(kf[1]) << 16);
    ku[1] = (unsigned)f2bf(kf[2]) | ((unsigned)f2bf(kf[3]) << 16);
    vu[0] = (unsigned)f2bf(vf[0]) | ((unsigned)f2bf(vf[1]) << 16);
    vu[1] = (unsigned)f2bf(vf[2]) | ((unsigned)f2bf(vf[3]) << 16);
    *(uint2v*)&Kt[row * 64 + dc * 4] = ku;
    *(uint2v*)&Vt[row * 64 + dc * 4] = vu;
  }
  __syncthreads();

#pragma unroll
  for (int c = 0; c < 4; ++c) {            // K fragments (1024 chunks over 128 keys)
    const int idx = c * 256 + tid;
    const int l31 = idx & 31, hi = (idx >> 5) & 1, d4 = (idx >> 6) & 3, kb = idx >> 8;
    const int tau = kb >> 1, kb2 = kb & 1;
    short8 v = *(const short8*)&Kt[(kb * 32 + l31) * 64 + d4 * 16 + hi * 8];
    *(short8*)&wt[tau * 8192 + (((kb2 * 4 + d4) * 2 + hi) * 32 + l31) * 8] = v;
  }
#pragma unroll
  for (int c = 0; c < 4; ++c) {            // V fragments
    const int idx = c * 256 + tid;
    const int l31 = idx & 31, dt = (idx >> 5) & 1, hi = (idx >> 6) & 1, k16 = idx >> 7;
    const int tau = k16 >> 2, k162 = k16 & 3;
    const int d = dt * 32 + l31, kb0 = k16 * 16 + hi * 8;
    short8 v;
#pragma unroll
    for (int j = 0; j < 8; ++j) v[j] = (short)Vt[(kb0 + j) * 64 + d];
    *(short8*)&wt[tau * 8192 + 4096 + (((k162 * 2 + hi) * 64) + dt * 32 + l31) * 8] = v;
  }
}

// ---------------------------------------------------------------------------
// Flash attention. 4 waves x 64 q-rows (2 q-sets); KT=64 double-buffered
// (32 KB LDS -> 4 blocks/CU with split grid). SPLIT: each block does half the
// KV range, emits unnormalized bf16 partial + f32 lsum (shift-free softmax is
// directly combinable).
// ---------------------------------------------------------------------------
template <bool SPLIT>
__global__ __launch_bounds__(256, 2)
void fattn(const float* __restrict__ Qp,
           const unsigned short* __restrict__ ws,
           float* __restrict__ Op) {
  __shared__ __align__(16) char lds[2][16384];   // [buf][K 8KB | V 8KB]

  const int tid  = threadIdx.x;
  const int lane = tid & 63;
  const int w    = tid >> 6;          // 0..3
  const int hi   = lane >> 5;
  const int l31  = lane & 31;

  int bh, qt, sh, rid;
  if (SPLIT) {                        // 1024 wgs: 128/XCD -> 4 bh per XCD L2
    const int id = blockIdx.x;
    rid = (id & 7) * 128 + (id >> 3);
    bh = rid >> 5; qt = (rid >> 1) & 15; sh = rid & 1;
  } else {                            // 512 wgs
    const int id = blockIdx.x;
    rid = (id & 7) * 64 + (id >> 3);
    bh = rid >> 4; qt = rid & 15; sh = 0;
  }
  const int NTloc = SPLIT ? 32 : 64;
  const int t0    = sh * 32;
  const int q0    = qt * 256 + w * 64;

  const int b = bh >> 4, h = bh & 15;
  const float* Qb = Qp + (size_t)b * SEQ * DMODEL + (size_t)h * DH;
  const char* wsb = (const char*)(ws + (size_t)bh * NT64 * 8192);

  // Q B-frags for both q-sets (col=q=l31, k: d = d4*16 + hi*8 + i)
  short8 qb[2][4];
#pragma unroll
  for (int s = 0; s < 2; ++s) {
    const float* qr = Qb + (size_t)(q0 + s * 32 + l31) * DMODEL;
    const float sc = 0.125f * LOG2E;
#pragma unroll
    for (int d4 = 0; d4 < 4; ++d4) {
      const float* p = qr + d4 * 16 + hi * 8;
      f32x4 f0 = *(const f32x4*)p;
      f32x4 f1 = *(const f32x4*)(p + 4);
      short8 v;
#pragma unroll
      for (int i = 0; i < 4; ++i) {
        v[i]     = (short)f2bf(f0[i] * sc);
        v[i + 4] = (short)f2bf(f1[i] * sc);
      }
      qb[s][d4] = v;
    }
  }

  f32x16 ZERO;
#pragma unroll
  for (int r = 0; r < 16; ++r) ZERO[r] = 0.f;
  f32x16 acc[2][2];                   // [qset][dt]
#pragma unroll
  for (int s = 0; s < 2; ++s)
#pragma unroll
    for (int dt = 0; dt < 2; ++dt) acc[s][dt] = ZERO;
  float lsum[2] = {0.f, 0.f};

  const int laneK = hi * 512 + l31 * 16;
  const int laneV = hi * 1024 + l31 * 16;

  // stage one 16KB 64-key tile: 4 x global_load_lds 16B/thread, linear
#define STAGE(buf_, tau_)                                                     \
  {                                                                           \
    const char* src_ = wsb + (size_t)(tau_) * 16384;                          \
    char* dst_ = &lds[buf_][0];                                               \
    _Pragma("unroll")                                                         \
    for (int c_ = 0; c_ < 4; ++c_) {                                          \
      __builtin_amdgcn_global_load_lds(                                       \
          (const __attribute__((address_space(1))) void*)(src_ + c_ * 4096 +  \
                                                          tid * 16),          \
          (__attribute__((address_space(3))) void*)(dst_ + c_ * 4096 +        \
                                                    tid * 16),                \
          16, 0, 0);                                                          \
    }                                                                         \
  }

  STAGE(0, t0);
  __syncthreads();

  for (int t = 0; t < NTloc; ++t) {
    const int buf = t & 1;
    if (t + 1 < NTloc) STAGE(buf ^ 1, t0 + t + 1);
    const char* Lk = &lds[buf][0];
    const char* Lv = &lds[buf][8192];

#pragma unroll
    for (int kb = 0; kb < 2; ++kb) {
      short8 ka[4];
#pragma unroll
      for (int d4 = 0; d4 < 4; ++d4)
        ka[d4] = *(const short8*)(Lk + kb * 4096 + d4 * 1024 + laneK);
      f32x16 zA, zB;
      __builtin_amdgcn_s_setprio(1);
      zA = __builtin_amdgcn_mfma_f32_32x32x16_bf16(ka[0], qb[0][0], ZERO, 0, 0, 0);
      zB = __builtin_amdgcn_mfma_f32_32x32x16_bf16(ka[0], qb[1][0], ZERO, 0, 0, 0);
      zA = __builtin_amdgcn_mfma_f32_32x32x16_bf16(ka[1], qb[0][1], zA, 0, 0, 0);
      zB = __builtin_amdgcn_mfma_f32_32x32x16_bf16(ka[1], qb[1][1], zB, 0, 0, 0);
      zA = __builtin_amdgcn_mfma_f32_32x32x16_bf16(ka[2], qb[0][2], zA, 0, 0, 0);
      zB = __builtin_amdgcn_mfma_f32_32x32x16_bf16(ka[2], qb[1][2], zB, 0, 0, 0);
      zA = __builtin_amdgcn_mfma_f32_32x32x16_bf16(ka[3], qb[0][3], zA, 0, 0, 0);
      zB = __builtin_amdgcn_mfma_f32_32x32x16_bf16(ka[3], qb[1][3], zB, 0, 0, 0);
      __builtin_amdgcn_s_setprio(0);

      // shift-free softmax: p = 2^s
#pragma unroll
      for (int r = 0; r < 16; ++r) zA[r] = __builtin_amdgcn_exp2f(zA[r]);
#pragma unroll
      for (int r = 0; r < 16; ++r) zB[r] = __builtin_amdgcn_exp2f(zB[r]);
      {
        float a0 = (zA[0] + zA[1]) + (zA[2] + zA[3]);
        float a1 = (zA[4] + zA[5]) + (zA[6] + zA[7]);
        float a2 = (zA[8] + zA[9]) + (zA[10] + zA[11]);
        float a3 = (zA[12] + zA[13]) + (zA[14] + zA[15]);
        lsum[0] += (a0 + a1) + (a2 + a3);
        float b0 = (zB[0] + zB[1]) + (zB[2] + zB[3]);
        float b1 = (zB[4] + zB[5]) + (zB[6] + zB[7]);
        float b2 = (zB[8] + zB[9]) + (zB[10] + zB[11]);
        float b3 = (zB[12] + zB[13]) + (zB[14] + zB[15]);
        lsum[1] += (b0 + b1) + (b2 + b3);
      }

#pragma unroll
      for (int s = 0; s < 2; ++s) {
        const int R = 8 * s;
        unsigned a0 = cvtpk_bf16(zA[R + 0], zA[R + 1]);
        unsigned c0 = cvtpk_bf16(zA[R + 4], zA[R + 5]);
        unsigned a1 = cvtpk_bf16(zA[R + 2], zA[R + 3]);
        unsigned c1 = cvtpk_bf16(zA[R + 6], zA[R + 7]);
        asm("v_permlane32_swap_b32 %0, %1" : "+v"(a0), "+v"(c0));
        asm("v_permlane32_swap_b32 %0, %1" : "+v"(a1), "+v"(c1));
        union { unsigned u[4]; short8 s8; } pwA;
        pwA.u[0] = a0; pwA.u[1] = a1; pwA.u[2] = c0; pwA.u[3] = c1;
        unsigned d0 = cvtpk_bf16(zB[R + 0], zB[R + 1]);
        unsigned e0 = cvtpk_bf16(zB[R + 4], zB[R + 5]);
        unsigned d1 = cvtpk_bf16(zB[R + 2], zB[R + 3]);
        unsigned e1 = cvtpk_bf16(zB[R + 6], zB[R + 7]);
        asm("v_permlane32_swap_b32 %0, %1" : "+v"(d0), "+v"(e0));
        asm("v_permlane32_swap_b32 %0, %1" : "+v"(d1), "+v"(e1));
        union { unsigned u[4]; short8 s8; } pwB;
        pwB.u[0] = d0; pwB.u[1] = d1; pwB.u[2] = e0; pwB.u[3] = e1;

        const int k16 = kb * 2 + s;
        short8 vb0 = *(const short8*)(Lv + k16 * 2048 + laneV);
        short8 vb1 = *(const short8*)(Lv + k16 * 2048 + 512 + laneV);
        __builtin_amdgcn_s_setprio(1);
        acc[0][0] = __builtin_amdgcn_mfma_f32_32x32x16_bf16(pwA.s8, vb0, acc[0][0], 0, 0, 0);
        acc[0][1] = __builtin_amdgcn_mfma_f32_32x32x16_bf16(pwA.s8, vb1, acc[0][1], 0, 0, 0);
        acc[1][0] = __builtin_amdgcn_mfma_f32_32x32x16_bf16(pwB.s8, vb0, acc[1][0], 0, 0, 0);
        acc[1][1] = __builtin_amdgcn_mfma_f32_32x32x16_bf16(pwB.s8, vb1, acc[1][1], 0, 0, 0);
        __builtin_amdgcn_s_setprio(0);
      }
    }
    __syncthreads();
  }

  if (SPLIT) {
    unsigned short* part = (unsigned short*)((char*)nullptr);  // set below
    // partials region starts at WS_KV_BYTES
    part = (unsigned short*)((const char*)ws + WS_KV_BYTES) + (size_t)rid * 16384;
    float* lout = (float*)((const char*)ws + WS_KV_BYTES + WS_KV_BYTES) + (size_t)rid * 256;
#pragma unroll
    for (int s = 0; s < 2; ++s) {
      const float lt = lsum[s] + __shfl_xor(lsum[s], 32, 64);
      if (hi == 0) lout[w * 64 + s * 32 + l31] = lt;
#pragma unroll
      for (int dt = 0; dt < 2; ++dt)
#pragma unroll
        for (int r = 0; r < 16; ++r) {
          const int qrow = (r & 3) + 8 * (r >> 2) + 4 * hi;
          part[(w * 64 + s * 32 + qrow) * 64 + dt * 32 + l31] = f2bf(acc[s][dt][r]);
        }
    }
  } else {
#pragma unroll
    for (int s = 0; s < 2; ++s) {
      const float lt  = lsum[s] + __shfl_xor(lsum[s], 32, 64);
      const float inv = 1.0f / lt;
#pragma unroll
      for (int dt = 0; dt < 2; ++dt)
#pragma unroll
        for (int r = 0; r < 16; ++r) {
          const int qrow = (r & 3) + 8 * (r >> 2) + 4 * hi;
          const float iv = __shfl(inv, qrow + (lane & 32), 64);
          const size_t row = (size_t)bh * SEQ + q0 + s * 32 + qrow;
          Op[row * DH + dt * 32 + l31] = acc[s][dt][r] * iv;
        }
    }
  }
}

// ---------------------------------------------------------------------------
// Combine: O = (A0 + A1) / (l0 + l1). 8 d-elements per thread.
// ---------------------------------------------------------------------------
__global__ __launch_bounds__(256)
void combine(const unsigned short* __restrict__ ws, float* __restrict__ Op) {
  const unsigned short* part = (const unsigned short*)((const char*)ws + WS_KV_BYTES);
  const float* lsum = (const float*)((const char*)ws + 2 * WS_KV_BYTES);
  const int gid = blockIdx.x * 256 + threadIdx.x;   // 1,048,576 threads
  const int bq = gid >> 11;                         // 0..511 (bh*16+qt)
  const int rem = gid & 2047;
  const int q = rem >> 3, dc = rem & 7;
  const int pid0 = bq * 2, pid1 = pid0 + 1;
  short8 A0 = *(const short8*)&part[(size_t)pid0 * 16384 + q * 64 + dc * 8];
  short8 A1 = *(const short8*)&part[(size_t)pid1 * 16384 + q * 64 + dc * 8];
  const float l = lsum[pid0 * 256 + q] + lsum[pid1 * 256 + q];
  const float inv = 1.0f / l;
  const int bh = bq >> 4, qt = bq & 15;
  float* o = Op + ((size_t)bh * SEQ + qt * 256 + q) * DH + dc * 8;
  f32x4 o0, o1;
#pragma unroll
  for (int j = 0; j < 4; ++j) {
    o0[j] = (bf2f((unsigned short)A0[j]) + bf2f((unsigned short)A1[j])) * inv;
    o1[j] = (bf2f((unsigned short)A0[j + 4]) + bf2f((unsigned short)A1[j + 4])) * inv;
  }
  *(f32x4*)o = o0;
  *(f32x4*)(o + 4) = o1;
}

extern "C" void kernel_launch(void* const* d_in, const int* in_sizes, int n_in,
                              void* d_out, int out_size, void* d_ws, size_t ws_size,
                              hipStream_t stream) {
  const float* Q = (const float*)d_in[0];
  const float* K = (const float*)d_in[1];
  const float* V = (const float*)d_in[2];
  float* O = (float*)d_out;
  unsigned short* ws = (unsigned short*)d_ws;

  prep<<<dim3(NBH * 32), dim3(256), 0, stream>>>(K, V, ws);
  if (ws_size >= WS_NEED_SPLIT) {
    fattn<true><<<dim3(1024), dim3(256), 0, stream>>>(Q, ws, O);
    combine<<<dim3(4096), dim3(256), 0, stream>>>(ws, O);
  } else {
    fattn<false><<<dim3(512), dim3(256), 0, stream>>>(Q, ws, O);
  }
}